// Round 8
// baseline (6201.669 us; speedup 1.0000x reference)
//
#include <hip/hip_runtime.h>
#include <math.h>

#define B   64
#define T   512
#define I0  256
#define H   512
#define M   (B*T)

#define NGR 4             // batch groups (16 rows each -> MFMA M=16)
#define BGR 16
#define RSLOTS 4          // ring depth; epoch-gated reuse, skew<=1 proven
#define SLOT_US (B*H)     // 32768 us per slot
#define GRP_US  (BGR*H)   // 8192 us per group region
#define RING_US ((size_t)RSLOTS*SLOT_US)   // 256KB per ring
#define POLL_BUDGET 1000000L

typedef __attribute__((ext_vector_type(8))) short short8;
typedef __attribute__((ext_vector_type(4))) float floatx4;
typedef __attribute__((ext_vector_type(2))) unsigned long long u64x2;
typedef unsigned long long u64;

static __device__ __forceinline__ unsigned short f2bf(float f) {
  unsigned u = __float_as_uint(f);
  u += 0x7fff + ((u >> 16) & 1);          // RNE
  return (unsigned short)(u >> 16);
}
static __device__ __forceinline__ float bf2f(unsigned short u) {
  return __uint_as_float((unsigned)u << 16);
}
// fast tanh: 1 - 2/(e^{2x}+1). |err| ~1e-6, saturates correctly, no NaN.
static __device__ __forceinline__ float ftanh(float x) {
  float e = __expf(2.0f * x);
  return 1.0f - 2.0f * __builtin_amdgcn_rcpf(e + 1.0f);
}

// ---------------------------------------------------------------------------
// Pack [H][H] fp32 weight into bf16 B-fragment lane order:
// dst layout [tile=32][kt=16][lane=64][8 us]
// ---------------------------------------------------------------------------
__global__ __launch_bounds__(256)
void pack_w(const float* __restrict__ W, unsigned short* __restrict__ dst) {
  int idx = blockIdx.x * 256 + threadIdx.x;   // over 16*2*16*64 = 32768
  int l = idx & 63, i = (idx >> 6) & 15, tau = (idx >> 10) & 1, c = idx >> 11;
  int col = c * 32 + tau * 16 + (l & 15);
  int k0  = i * 32 + (l >> 4) * 8;
  const float* src = &W[col * H + k0];
  unsigned v[4];
  #pragma unroll
  for (int j = 0; j < 4; ++j) {
    unsigned lo = f2bf(src[2*j]);
    unsigned hi = f2bf(src[2*j + 1]);
    v[j] = lo | (hi << 16);
  }
  *(uint4*)&dst[(size_t)idx * 8] = make_uint4(v[0], v[1], v[2], v[3]);
}

// ---------------------------------------------------------------------------
// Pack Wih0 [H][I0] fp32 -> bf16 B-frags: [tile=32][kt=8][lane=64][8 us]
// ---------------------------------------------------------------------------
__global__ __launch_bounds__(256)
void pack_wx(const float* __restrict__ W, unsigned short* __restrict__ dst) {
  int idx = blockIdx.x * 256 + threadIdx.x;   // over 32*8*64 = 16384
  int l = idx & 63, kt = (idx >> 6) & 7, t = idx >> 9;
  int col = t * 16 + (l & 15);
  int k0  = kt * 32 + (l >> 4) * 8;
  const float* src = &W[col * I0 + k0];
  unsigned v[4];
  #pragma unroll
  for (int j = 0; j < 4; ++j) {
    unsigned lo = f2bf(src[2*j]);
    unsigned hi = f2bf(src[2*j + 1]);
    v[j] = lo | (hi << 16);
  }
  *(uint4*)&dst[(size_t)idx * 8] = make_uint4(v[0], v[1], v[2], v[3]);
}

// ---------------------------------------------------------------------------
// MFMA input-projection GEMM: xwb[M][H] = bf16( x[M][I0] @ Wih0^T ).
// Split-A (x = hi + lo bf16) keeps accuracy at the fp32-GEMM level.
// Block: 64 rows x 256 cols; packed W half staged to LDS (128KB).
// ---------------------------------------------------------------------------
__global__ __launch_bounds__(256)
void gemm_mfma(const float* __restrict__ x, const unsigned short* __restrict__ wpx,
               unsigned short* __restrict__ xwb) {
  extern __shared__ unsigned short wl[];   // [16 tiles][8 kt][64][8] = 128KB
  const int tid = threadIdx.x, wv = tid >> 6, lane = tid & 63;
  const int mrow = lane & 15, quad = lane >> 4;
  const int m0 = blockIdx.x * 64 + wv * 16;
  const int n0 = blockIdx.y * 256;
  {
    const uint4* s = (const uint4*)(wpx + (size_t)(n0 / 16) * 4096);
    uint4* d = (uint4*)wl;
    for (int i = tid; i < 8192; i += 256) d[i] = s[i];
  }
  short8 ah[8], al[8];
  const float* xr = x + (size_t)(m0 + mrow) * I0;
  #pragma unroll
  for (int kt = 0; kt < 8; ++kt) {
    float4 u = *(const float4*)&xr[kt * 32 + quad * 8];
    float4 v = *(const float4*)&xr[kt * 32 + quad * 8 + 4];
    float f[8] = {u.x,u.y,u.z,u.w,v.x,v.y,v.z,v.w};
    union { unsigned w[4]; short8 s; } hi, lo;
    #pragma unroll
    for (int j = 0; j < 4; ++j) {
      unsigned short h0 = f2bf(f[2*j]),   l0 = f2bf(f[2*j]   - bf2f(h0));
      unsigned short h1 = f2bf(f[2*j+1]), l1 = f2bf(f[2*j+1] - bf2f(h1));
      hi.w[j] = (unsigned)h0 | ((unsigned)h1 << 16);
      lo.w[j] = (unsigned)l0 | ((unsigned)l1 << 16);
    }
    ah[kt] = hi.s; al[kt] = lo.s;
  }
  __syncthreads();
  for (int ct = 0; ct < 16; ++ct) {
    floatx4 acc = {0.f,0.f,0.f,0.f};
    #pragma unroll
    for (int kt = 0; kt < 8; ++kt) {
      short8 b = *(const short8*)(wl + ((size_t)(ct * 8 + kt) * 64 + lane) * 8);
      acc = __builtin_amdgcn_mfma_f32_16x16x32_bf16(al[kt], b, acc, 0, 0, 0);
      acc = __builtin_amdgcn_mfma_f32_16x16x32_bf16(ah[kt], b, acc, 0, 0, 0);
    }
    #pragma unroll
    for (int i = 0; i < 4; ++i)
      xwb[(size_t)(m0 + quad*4 + i) * H + n0 + ct*16 + mrow] = f2bf(acc[i]);
  }
}

// ---------------------------------------------------------------------------
// Lockstep recurrence, epoch-flag protocol (R1's proven 2-hop, de-fattened).
// 64 blocks x 256 thr; block (g,wp): batch rows [16g,16g+16), cols
// [32wp,32wp+32), both layers. Ring: dual-coalesced [slot][g][kt=16][row=16]
// [32cols x 2B] (R7-verified): producer stores = 4 x (4x32B segs); consumer
// loads = coalesced A-frags straight into MFMA operands.
//
// Publish: 4 ring stores (relaxed) -> epoch release-store (per-wave word,
// value r+1; release drains only this wave's stores). Detect: 1-instr poll
// of the 32 epoch words + s_sleep(1) backoff (cheap on the fabric), then
// ONE batched fragment load. No sentinels, no re-arm stores, no data-poll.
//
// Round r: waves 0/1 = L1 step r (poll ring0 epochs>=r, load ring0[r-1]);
// waves 2/3 = L2 step t=r-2 (check ring1 epochs>=t — one-round slack,
// near-instant; h1[t] via LDS hs dbuf staged by L1 last round). One
// lgkm-only s_barrier per round. Epoch gating bounds global skew to <=1;
// depth-4 ring slot distances verified safe. Budgets bail, never hang.
// ---------------------------------------------------------------------------
__global__ __launch_bounds__(256, 1)
void rnn_fused(const unsigned short* __restrict__ xwb,  // [B][T][H] bf16
               const unsigned short* __restrict__ wp0,  // Whh0 packed
               const unsigned short* __restrict__ wp1,  // Wih1 packed
               const unsigned short* __restrict__ wp2,  // Whh1 packed
               unsigned short* __restrict__ ring0,      // [4][B][H] bf16
               unsigned short* __restrict__ ring1,      // [4][B][H] bf16
               float* __restrict__ dout,                // [B][T][H]
               int* __restrict__ flags)                 // [NGR][2][32] epochs
{
  extern __shared__ unsigned short smem[];
  unsigned short* Wi1 = smem;             // [2 tiles][16][64][8] = 16384 us
  unsigned short* hs  = Wi1 + 16384;      // [2][16][64][8] dbuf   = 16384 us

  const int tid  = threadIdx.x;
  const int wv   = tid >> 6;
  const int lane = tid & 63;
  const int mrow = lane & 15, quad = lane >> 4;
  const int g  = blockIdx.x & 3;
  const int wp = blockIdx.x >> 2;
  const int b0 = g * BGR;
  const int tau  = wv & 1;
  const int tv   = 2*wp + tau;
  const int ccol = tv*16 + mrow;
  const int poff = wp*512 + tau*16 + mrow;       // ring store offset (us)
  const int lq   = mrow*8 + quad*2;              // ring load offset (u64)

  {   // stage Wih1 tile pair into LDS
    const uint4* s1 = (const uint4*)(wp1 + (size_t)(2*wp) * 8192);
    uint4* d1 = (uint4*)Wi1;
    for (int i = tid; i < 2048; i += 256) d1[i] = s1[i];
  }
  // recurrence-critical weights -> registers (L1: Whh0, L2: Whh1)
  short8 wreg[16];
  {
    const unsigned short* wsrc = (wv < 2) ? wp0 : wp2;
    #pragma unroll
    for (int kt = 0; kt < 16; ++kt)
      wreg[kt] = *(const short8*)(wsrc + (size_t)((tv*16 + kt)*64 + lane) * 8);
  }
  __syncthreads();

  int* fl0 = flags + g * 64;          // ring0 epochs [32]
  int* fl1 = fl0 + 32;                // ring1 epochs [32]
  int* myep0 = fl0 + wp*2 + tau;
  int* myep1 = fl1 + wp*2 + tau;
  long cnt = 0;

  for (int r = 0; r <= T + 1; ++r) {
    if (wv < 2) {
      // ============================ layer 1 ============================
      unsigned short xus[4];
      if (r < T) {
        #pragma unroll
        for (int i = 0; i < 4; ++i)
          xus[i] = xwb[((size_t)(b0 + quad*4 + i) * T + r) * H + ccol];
      }
      u64 hv[32];
      if (r >= 1 && r <= T) {
        for (;;) {   // 1-instr epoch poll, sleep backoff
          int ep = __hip_atomic_load(fl0 + (lane & 31),
                                     __ATOMIC_RELAXED, __HIP_MEMORY_SCOPE_AGENT);
          if (__all(ep >= r) || ++cnt > POLL_BUDGET) break;
          __builtin_amdgcn_s_sleep(1);
        }
        __builtin_amdgcn_sched_barrier(0);
        const u64* rb = (const u64*)(ring0
            + (size_t)((r-1) & (RSLOTS-1)) * SLOT_US + g * GRP_US);
        #pragma unroll
        for (int kt = 0; kt < 16; ++kt) {       // ONE batched fragment load
          hv[2*kt]   = __hip_atomic_load(rb + kt*128 + lq,
                                         __ATOMIC_RELAXED, __HIP_MEMORY_SCOPE_AGENT);
          hv[2*kt+1] = __hip_atomic_load(rb + kt*128 + lq + 1,
                                         __ATOMIC_RELAXED, __HIP_MEMORY_SCOPE_AGENT);
        }
      }
      if (r < T) {
        floatx4 aA = {0.f,0.f,0.f,0.f}, aB = {0.f,0.f,0.f,0.f};
        if (r >= 1) {
          #pragma unroll
          for (int kt = 0; kt < 16; kt += 2) {  // 2 chains halve dep latency
            union { u64 u[2]; short8 s; } a, b;
            a.u[0] = hv[2*kt];   a.u[1] = hv[2*kt+1];
            b.u[0] = hv[2*kt+2]; b.u[1] = hv[2*kt+3];
            aA = __builtin_amdgcn_mfma_f32_16x16x32_bf16(a.s, wreg[kt],   aA, 0, 0, 0);
            aB = __builtin_amdgcn_mfma_f32_16x16x32_bf16(b.s, wreg[kt+1], aB, 0, 0, 0);
          }
        }
        unsigned short* wdst = ring0 + (size_t)(r & (RSLOTS-1)) * SLOT_US + g*GRP_US;
        #pragma unroll
        for (int i = 0; i < 4; ++i) {           // publish (4 x 32B segments)
          float h = ftanh(aA[i] + aB[i] + bf2f(xus[i]));
          __hip_atomic_store(wdst + poff + (quad*4 + i)*32, f2bf(h),
                             __ATOMIC_RELAXED, __HIP_MEMORY_SCOPE_AGENT);
        }
        // release: drains THIS wave's stores, then epoch visible
        __hip_atomic_store(myep0, r + 1, __ATOMIC_RELEASE, __HIP_MEMORY_SCOPE_AGENT);
      }
      if (r >= 1 && r <= T) {
        // share polled h1[r-1] frags with L2 (consumed next round)
        unsigned short* hb = hs + (size_t)((r-1) & 1) * 8192;
        #pragma unroll
        for (int k8 = 0; k8 < 8; ++k8) {
          int kt = tau*8 + k8;
          u64x2 v; v.x = hv[2*kt]; v.y = hv[2*kt+1];
          *(u64x2*)(hb + ((size_t)(kt*64 + lane)) * 8) = v;
        }
      }
    } else {
      // ========================= layer 2 (t = r-2) =========================
      if (r >= 2) {
        const int t = r - 2;
        u64 gv[32];
        if (t >= 1) {
          for (;;) {   // one-round slack -> near-always instant
            int ep = __hip_atomic_load(fl1 + (lane & 31),
                                       __ATOMIC_RELAXED, __HIP_MEMORY_SCOPE_AGENT);
            if (__all(ep >= t) || ++cnt > POLL_BUDGET) break;
            __builtin_amdgcn_s_sleep(1);
          }
          __builtin_amdgcn_sched_barrier(0);
          const u64* rb1 = (const u64*)(ring1
              + (size_t)((t-1) & (RSLOTS-1)) * SLOT_US + g * GRP_US);
          #pragma unroll
          for (int kt = 0; kt < 16; ++kt) {     // latency hides under Wih1 MFMAs
            gv[2*kt]   = __hip_atomic_load(rb1 + kt*128 + lq,
                                           __ATOMIC_RELAXED, __HIP_MEMORY_SCOPE_AGENT);
            gv[2*kt+1] = __hip_atomic_load(rb1 + kt*128 + lq + 1,
                                           __ATOMIC_RELAXED, __HIP_MEMORY_SCOPE_AGENT);
          }
        }
        const unsigned short* hb  = hs + (size_t)(t & 1) * 8192;   // h1[t]
        const unsigned short* wil = Wi1 + tau * 8192;
        floatx4 pa = {0.f,0.f,0.f,0.f}, pb = {0.f,0.f,0.f,0.f};
        #pragma unroll
        for (int kt = 0; kt < 16; kt += 2) {       // Wih1 * h1[t]
          union { u64 u[2]; short8 s; } a, b;
          u64x2 va = *(const u64x2*)(hb + ((size_t)((kt  )*64 + lane)) * 8);
          u64x2 vb = *(const u64x2*)(hb + ((size_t)((kt+1)*64 + lane)) * 8);
          a.u[0] = va.x; a.u[1] = va.y; b.u[0] = vb.x; b.u[1] = vb.y;
          short8 w0 = *(const short8*)(wil + ((size_t)((kt  )*64 + lane)) * 8);
          short8 w1 = *(const short8*)(wil + ((size_t)((kt+1)*64 + lane)) * 8);
          pa = __builtin_amdgcn_mfma_f32_16x16x32_bf16(a.s, w0, pa, 0, 0, 0);
          pb = __builtin_amdgcn_mfma_f32_16x16x32_bf16(b.s, w1, pb, 0, 0, 0);
        }
        if (t >= 1) {
          #pragma unroll
          for (int kt = 0; kt < 16; kt += 2) {     // Whh1 * h2[t-1] (pure-reg)
            union { u64 u[2]; short8 s; } a, b;
            a.u[0] = gv[2*kt];   a.u[1] = gv[2*kt+1];
            b.u[0] = gv[2*kt+2]; b.u[1] = gv[2*kt+3];
            pa = __builtin_amdgcn_mfma_f32_16x16x32_bf16(a.s, wreg[kt],   pa, 0, 0, 0);
            pb = __builtin_amdgcn_mfma_f32_16x16x32_bf16(b.s, wreg[kt+1], pb, 0, 0, 0);
          }
        }
        unsigned short* wdst = ring1 + (size_t)(t & (RSLOTS-1)) * SLOT_US + g*GRP_US;
        float hv4[4];
        #pragma unroll
        for (int i = 0; i < 4; ++i) {              // ring publish first
          float v = ftanh(pa[i] + pb[i]);
          hv4[i] = v;
          __hip_atomic_store(wdst + poff + (quad*4 + i)*32, f2bf(v),
                             __ATOMIC_RELAXED, __HIP_MEMORY_SCOPE_AGENT);
        }
        __hip_atomic_store(myep1, t + 1, __ATOMIC_RELEASE, __HIP_MEMORY_SCOPE_AGENT);
        #pragma unroll
        for (int i = 0; i < 4; ++i)                // dout after the release
          dout[((size_t)(b0 + quad*4 + i) * T + t) * H + ccol] = hv4[i];
      }
    }
    // one barrier per round; drain LDS writes only (never vmcnt)
    asm volatile("s_waitcnt lgkmcnt(0)\n\ts_barrier" ::: "memory");
    __builtin_amdgcn_sched_barrier(0);
  }
}

#define SMEM_BYTES  ((16384 + 16384) * 2)   // 64KB (rnn)
#define SMEM_GEMM   131072                  // 128KB (gemm)

extern "C" void kernel_launch(void* const* d_in, const int* in_sizes, int n_in,
                              void* d_out, int out_size, void* d_ws, size_t ws_size,
                              hipStream_t stream) {
  const float* x    = (const float*)d_in[0];
  const float* Wih0 = (const float*)d_in[1];
  const float* Whh0 = (const float*)d_in[2];
  const float* Wih1 = (const float*)d_in[3];
  const float* Whh1 = (const float*)d_in[4];
  float* out = (float*)d_out;

  char* ws = (char*)d_ws;
  unsigned short* xwb = (unsigned short*)ws;                           // 32MB
  unsigned short* wp0 = (unsigned short*)(ws + (size_t)32*1024*1024);          // 512KB
  unsigned short* wp1 = (unsigned short*)(ws + (size_t)32*1024*1024 + 512*1024);
  unsigned short* wp2 = (unsigned short*)(ws + (size_t)32*1024*1024 + 1024*1024);
  unsigned short* wpx = (unsigned short*)(ws + (size_t)32*1024*1024 + 1536*1024); // 256KB
  unsigned short* ring0 = (unsigned short*)(ws + (size_t)32*1024*1024 + 1792*1024);
  unsigned short* ring1 = ring0 + RING_US;
  int* flags = (int*)(ring1 + RING_US);

  hipMemsetAsync(flags, 0, NGR * 64 * sizeof(int), stream);
  hipFuncSetAttribute((const void*)rnn_fused,
                      hipFuncAttributeMaxDynamicSharedMemorySize, SMEM_BYTES);
  hipFuncSetAttribute((const void*)gemm_mfma,
                      hipFuncAttributeMaxDynamicSharedMemorySize, SMEM_GEMM);

  pack_w<<<128, 256, 0, stream>>>(Whh0, wp0);
  pack_w<<<128, 256, 0, stream>>>(Wih1, wp1);
  pack_w<<<128, 256, 0, stream>>>(Whh1, wp2);
  pack_wx<<<64, 256, 0, stream>>>(Wih0, wpx);

  dim3 gg(M/64, H/256);
  gemm_mfma<<<gg, 256, SMEM_GEMM, stream>>>(x, wpx, xwb);

  rnn_fused<<<NGR * 16, 256, SMEM_BYTES, stream>>>(
      xwb, wp0, wp1, wp2, ring0, ring1, out, flags);
}

// Round 10
// 4883.658 us; speedup vs baseline: 1.2699x; 1.2699x over previous
//
#include <hip/hip_runtime.h>
#include <math.h>

#define B   64
#define T   512
#define I0  256
#define H   512
#define M   (B*T)

#define NGR 4             // batch groups (16 rows each -> MFMA M=16)
#define BGR 16
#define RSLOTS 4          // ring depth; epoch-gated reuse, skew<=1 proven
#define SLOT_US (B*H)     // 32768 us per slot
#define GRP_US  (BGR*H)   // 8192 us per group region
#define RING_US ((size_t)RSLOTS*SLOT_US)   // 256KB per ring
#define POLL_BUDGET 500000L

typedef __attribute__((ext_vector_type(8))) short short8;
typedef __attribute__((ext_vector_type(4))) float floatx4;
typedef __attribute__((ext_vector_type(2))) unsigned long long u64x2;
typedef unsigned long long u64;

static __device__ __forceinline__ unsigned short f2bf(float f) {
  unsigned u = __float_as_uint(f);
  u += 0x7fff + ((u >> 16) & 1);          // RNE
  return (unsigned short)(u >> 16);
}
static __device__ __forceinline__ float bf2f(unsigned short u) {
  return __uint_as_float((unsigned)u << 16);
}
// fast tanh: 1 - 2/(e^{2x}+1). |err| ~1e-6, saturates correctly, no NaN.
static __device__ __forceinline__ float ftanh(float x) {
  float e = __expf(2.0f * x);
  return 1.0f - 2.0f * __builtin_amdgcn_rcpf(e + 1.0f);
}

// ---------------------------------------------------------------------------
// Pack [H][H] fp32 weight into bf16 B-fragment lane order:
// dst layout [tile=32][kt=16][lane=64][8 us]
// ---------------------------------------------------------------------------
__global__ __launch_bounds__(256)
void pack_w(const float* __restrict__ W, unsigned short* __restrict__ dst) {
  int idx = blockIdx.x * 256 + threadIdx.x;   // over 16*2*16*64 = 32768
  int l = idx & 63, i = (idx >> 6) & 15, tau = (idx >> 10) & 1, c = idx >> 11;
  int col = c * 32 + tau * 16 + (l & 15);
  int k0  = i * 32 + (l >> 4) * 8;
  const float* src = &W[col * H + k0];
  unsigned v[4];
  #pragma unroll
  for (int j = 0; j < 4; ++j) {
    unsigned lo = f2bf(src[2*j]);
    unsigned hi = f2bf(src[2*j + 1]);
    v[j] = lo | (hi << 16);
  }
  *(uint4*)&dst[(size_t)idx * 8] = make_uint4(v[0], v[1], v[2], v[3]);
}

// ---------------------------------------------------------------------------
// Pack Wih0 [H][I0] fp32 -> bf16 B-frags: [tile=32][kt=8][lane=64][8 us]
// ---------------------------------------------------------------------------
__global__ __launch_bounds__(256)
void pack_wx(const float* __restrict__ W, unsigned short* __restrict__ dst) {
  int idx = blockIdx.x * 256 + threadIdx.x;   // over 32*8*64 = 16384
  int l = idx & 63, kt = (idx >> 6) & 7, t = idx >> 9;
  int col = t * 16 + (l & 15);
  int k0  = kt * 32 + (l >> 4) * 8;
  const float* src = &W[col * I0 + k0];
  unsigned v[4];
  #pragma unroll
  for (int j = 0; j < 4; ++j) {
    unsigned lo = f2bf(src[2*j]);
    unsigned hi = f2bf(src[2*j + 1]);
    v[j] = lo | (hi << 16);
  }
  *(uint4*)&dst[(size_t)idx * 8] = make_uint4(v[0], v[1], v[2], v[3]);
}

// ---------------------------------------------------------------------------
// MFMA input-projection GEMM: xwb[M][H] = bf16( x[M][I0] @ Wih0^T ).
// Split-A (x = hi + lo bf16) keeps accuracy at the fp32-GEMM level.
// ---------------------------------------------------------------------------
__global__ __launch_bounds__(256)
void gemm_mfma(const float* __restrict__ x, const unsigned short* __restrict__ wpx,
               unsigned short* __restrict__ xwb) {
  extern __shared__ unsigned short wl[];   // [16 tiles][8 kt][64][8] = 128KB
  const int tid = threadIdx.x, wv = tid >> 6, lane = tid & 63;
  const int mrow = lane & 15, quad = lane >> 4;
  const int m0 = blockIdx.x * 64 + wv * 16;
  const int n0 = blockIdx.y * 256;
  {
    const uint4* s = (const uint4*)(wpx + (size_t)(n0 / 16) * 4096);
    uint4* d = (uint4*)wl;
    for (int i = tid; i < 8192; i += 256) d[i] = s[i];
  }
  short8 ah[8], al[8];
  const float* xr = x + (size_t)(m0 + mrow) * I0;
  #pragma unroll
  for (int kt = 0; kt < 8; ++kt) {
    float4 u = *(const float4*)&xr[kt * 32 + quad * 8];
    float4 v = *(const float4*)&xr[kt * 32 + quad * 8 + 4];
    float f[8] = {u.x,u.y,u.z,u.w,v.x,v.y,v.z,v.w};
    union { unsigned w[4]; short8 s; } hi, lo;
    #pragma unroll
    for (int j = 0; j < 4; ++j) {
      unsigned short h0 = f2bf(f[2*j]),   l0 = f2bf(f[2*j]   - bf2f(h0));
      unsigned short h1 = f2bf(f[2*j+1]), l1 = f2bf(f[2*j+1] - bf2f(h1));
      hi.w[j] = (unsigned)h0 | ((unsigned)h1 << 16);
      lo.w[j] = (unsigned)l0 | ((unsigned)l1 << 16);
    }
    ah[kt] = hi.s; al[kt] = lo.s;
  }
  __syncthreads();
  for (int ct = 0; ct < 16; ++ct) {
    floatx4 acc = {0.f,0.f,0.f,0.f};
    #pragma unroll
    for (int kt = 0; kt < 8; ++kt) {
      short8 b = *(const short8*)(wl + ((size_t)(ct * 8 + kt) * 64 + lane) * 8);
      acc = __builtin_amdgcn_mfma_f32_16x16x32_bf16(al[kt], b, acc, 0, 0, 0);
      acc = __builtin_amdgcn_mfma_f32_16x16x32_bf16(ah[kt], b, acc, 0, 0, 0);
    }
    #pragma unroll
    for (int i = 0; i < 4; ++i)
      xwb[(size_t)(m0 + quad*4 + i) * H + n0 + ct*16 + mrow] = f2bf(acc[i]);
  }
}

// ---------------------------------------------------------------------------
// Lockstep recurrence, epoch-flag protocol. Same as round 8 except the
// publish fence: __ATOMIC_RELEASE (emits an L2 writeback per store on
// multi-XCD gfx950 -> 1.18GB WRITE_SIZE, 12.6us/step in R8) is replaced by
// `s_waitcnt vmcnt(0)` (drain THIS wave's 4 write-through ring stores)
// followed by a RELAXED epoch store — exactly R1's proven ordering
// (vmcnt-drain before relaxed flag; consumer sees flag -> reads data).
//
// Publish: 4 ring stores (relaxed) -> vmcnt(0) -> relaxed epoch store
// (per-wave word, no RMW serialization). Detect: 1-instr poll of the 32
// epoch words + s_sleep(1) backoff, then ONE batched fragment load.
// Round r: waves 0/1 = L1 step r; waves 2/3 = L2 step t=r-2 (one-round
// slack on ring1; h1[t] via LDS hs dbuf staged by L1 last round). One
// lgkm-only s_barrier per round. Depth-4 ring reuse is epoch-gated
// (producer reaches slot reuse only after all peers consumed it).
// cnt is cumulative: once budget trips, every poll breaks instantly.
// ---------------------------------------------------------------------------
__global__ __launch_bounds__(256, 1)
void rnn_fused(const unsigned short* __restrict__ xwb,  // [B][T][H] bf16
               const unsigned short* __restrict__ wp0,  // Whh0 packed
               const unsigned short* __restrict__ wp1,  // Wih1 packed
               const unsigned short* __restrict__ wp2,  // Whh1 packed
               unsigned short* __restrict__ ring0,      // [4][B][H] bf16
               unsigned short* __restrict__ ring1,      // [4][B][H] bf16
               float* __restrict__ dout,                // [B][T][H]
               int* __restrict__ flags)                 // [NGR][2][32] epochs
{
  extern __shared__ unsigned short smem[];
  unsigned short* Wi1 = smem;             // [2 tiles][16][64][8] = 16384 us
  unsigned short* hs  = Wi1 + 16384;      // [2][16][64][8] dbuf   = 16384 us

  const int tid  = threadIdx.x;
  const int wv   = tid >> 6;
  const int lane = tid & 63;
  const int mrow = lane & 15, quad = lane >> 4;
  const int g  = blockIdx.x & 3;
  const int wp = blockIdx.x >> 2;
  const int b0 = g * BGR;
  const int tau  = wv & 1;
  const int tv   = 2*wp + tau;
  const int ccol = tv*16 + mrow;
  const int poff = wp*512 + tau*16 + mrow;       // ring store offset (us)
  const int lq   = mrow*8 + quad*2;              // ring load offset (u64)

  {   // stage Wih1 tile pair into LDS
    const uint4* s1 = (const uint4*)(wp1 + (size_t)(2*wp) * 8192);
    uint4* d1 = (uint4*)Wi1;
    for (int i = tid; i < 2048; i += 256) d1[i] = s1[i];
  }
  // recurrence-critical weights -> registers (L1: Whh0, L2: Whh1)
  short8 wreg[16];
  {
    const unsigned short* wsrc = (wv < 2) ? wp0 : wp2;
    #pragma unroll
    for (int kt = 0; kt < 16; ++kt)
      wreg[kt] = *(const short8*)(wsrc + (size_t)((tv*16 + kt)*64 + lane) * 8);
  }
  __syncthreads();

  int* fl0 = flags + g * 64;          // ring0 epochs [32]
  int* fl1 = fl0 + 32;                // ring1 epochs [32]
  int* myep0 = fl0 + wp*2 + tau;
  int* myep1 = fl1 + wp*2 + tau;
  long cnt = 0;

  for (int r = 0; r <= T + 1; ++r) {
    if (wv < 2) {
      // ============================ layer 1 ============================
      unsigned short xus[4];
      if (r < T) {
        #pragma unroll
        for (int i = 0; i < 4; ++i)
          xus[i] = xwb[((size_t)(b0 + quad*4 + i) * T + r) * H + ccol];
      }
      u64 hv[32];
      if (r >= 1 && r <= T) {
        for (;;) {   // 1-instr epoch poll, sleep backoff
          int ep = __hip_atomic_load(fl0 + (lane & 31),
                                     __ATOMIC_RELAXED, __HIP_MEMORY_SCOPE_AGENT);
          if (__all(ep >= r) || ++cnt > POLL_BUDGET) break;
          __builtin_amdgcn_s_sleep(1);
        }
        __builtin_amdgcn_sched_barrier(0);
        const u64* rb = (const u64*)(ring0
            + (size_t)((r-1) & (RSLOTS-1)) * SLOT_US + g * GRP_US);
        #pragma unroll
        for (int kt = 0; kt < 16; ++kt) {       // ONE batched fragment load
          hv[2*kt]   = __hip_atomic_load(rb + kt*128 + lq,
                                         __ATOMIC_RELAXED, __HIP_MEMORY_SCOPE_AGENT);
          hv[2*kt+1] = __hip_atomic_load(rb + kt*128 + lq + 1,
                                         __ATOMIC_RELAXED, __HIP_MEMORY_SCOPE_AGENT);
        }
      }
      if (r < T) {
        floatx4 aA = {0.f,0.f,0.f,0.f}, aB = {0.f,0.f,0.f,0.f};
        if (r >= 1) {
          #pragma unroll
          for (int kt = 0; kt < 16; kt += 2) {  // 2 chains halve dep latency
            union { u64 u[2]; short8 s; } a, b;
            a.u[0] = hv[2*kt];   a.u[1] = hv[2*kt+1];
            b.u[0] = hv[2*kt+2]; b.u[1] = hv[2*kt+3];
            aA = __builtin_amdgcn_mfma_f32_16x16x32_bf16(a.s, wreg[kt],   aA, 0, 0, 0);
            aB = __builtin_amdgcn_mfma_f32_16x16x32_bf16(b.s, wreg[kt+1], aB, 0, 0, 0);
          }
        }
        unsigned short* wdst = ring0 + (size_t)(r & (RSLOTS-1)) * SLOT_US + g*GRP_US;
        #pragma unroll
        for (int i = 0; i < 4; ++i) {           // publish (4 x 32B segments)
          float h = ftanh(aA[i] + aB[i] + bf2f(xus[i]));
          __hip_atomic_store(wdst + poff + (quad*4 + i)*32, f2bf(h),
                             __ATOMIC_RELAXED, __HIP_MEMORY_SCOPE_AGENT);
        }
        // drain THIS wave's write-through stores, then relaxed epoch store
        asm volatile("s_waitcnt vmcnt(0)" ::: "memory");
        __builtin_amdgcn_sched_barrier(0);
        __hip_atomic_store(myep0, r + 1, __ATOMIC_RELAXED, __HIP_MEMORY_SCOPE_AGENT);
      }
      if (r >= 1 && r <= T) {
        // share polled h1[r-1] frags with L2 (consumed next round)
        unsigned short* hb = hs + (size_t)((r-1) & 1) * 8192;
        #pragma unroll
        for (int k8 = 0; k8 < 8; ++k8) {
          int kt = tau*8 + k8;
          u64x2 v; v.x = hv[2*kt]; v.y = hv[2*kt+1];
          *(u64x2*)(hb + ((size_t)(kt*64 + lane)) * 8) = v;
        }
      }
    } else {
      // ========================= layer 2 (t = r-2) =========================
      if (r >= 2) {
        const int t = r - 2;
        u64 gv[32];
        if (t >= 1) {
          for (;;) {   // one-round slack -> near-always instant
            int ep = __hip_atomic_load(fl1 + (lane & 31),
                                       __ATOMIC_RELAXED, __HIP_MEMORY_SCOPE_AGENT);
            if (__all(ep >= t) || ++cnt > POLL_BUDGET) break;
            __builtin_amdgcn_s_sleep(1);
          }
          __builtin_amdgcn_sched_barrier(0);
          const u64* rb1 = (const u64*)(ring1
              + (size_t)((t-1) & (RSLOTS-1)) * SLOT_US + g * GRP_US);
          #pragma unroll
          for (int kt = 0; kt < 16; ++kt) {     // latency hides under Wih1 MFMAs
            gv[2*kt]   = __hip_atomic_load(rb1 + kt*128 + lq,
                                           __ATOMIC_RELAXED, __HIP_MEMORY_SCOPE_AGENT);
            gv[2*kt+1] = __hip_atomic_load(rb1 + kt*128 + lq + 1,
                                           __ATOMIC_RELAXED, __HIP_MEMORY_SCOPE_AGENT);
          }
        }
        const unsigned short* hb  = hs + (size_t)(t & 1) * 8192;   // h1[t]
        const unsigned short* wil = Wi1 + tau * 8192;
        floatx4 pa = {0.f,0.f,0.f,0.f}, pb = {0.f,0.f,0.f,0.f};
        #pragma unroll
        for (int kt = 0; kt < 16; kt += 2) {       // Wih1 * h1[t]
          union { u64 u[2]; short8 s; } a, b;
          u64x2 va = *(const u64x2*)(hb + ((size_t)((kt  )*64 + lane)) * 8);
          u64x2 vb = *(const u64x2*)(hb + ((size_t)((kt+1)*64 + lane)) * 8);
          a.u[0] = va.x; a.u[1] = va.y; b.u[0] = vb.x; b.u[1] = vb.y;
          short8 w0 = *(const short8*)(wil + ((size_t)((kt  )*64 + lane)) * 8);
          short8 w1 = *(const short8*)(wil + ((size_t)((kt+1)*64 + lane)) * 8);
          pa = __builtin_amdgcn_mfma_f32_16x16x32_bf16(a.s, w0, pa, 0, 0, 0);
          pb = __builtin_amdgcn_mfma_f32_16x16x32_bf16(b.s, w1, pb, 0, 0, 0);
        }
        if (t >= 1) {
          #pragma unroll
          for (int kt = 0; kt < 16; kt += 2) {     // Whh1 * h2[t-1] (pure-reg)
            union { u64 u[2]; short8 s; } a, b;
            a.u[0] = gv[2*kt];   a.u[1] = gv[2*kt+1];
            b.u[0] = gv[2*kt+2]; b.u[1] = gv[2*kt+3];
            pa = __builtin_amdgcn_mfma_f32_16x16x32_bf16(a.s, wreg[kt],   pa, 0, 0, 0);
            pb = __builtin_amdgcn_mfma_f32_16x16x32_bf16(b.s, wreg[kt+1], pb, 0, 0, 0);
          }
        }
        unsigned short* wdst = ring1 + (size_t)(t & (RSLOTS-1)) * SLOT_US + g*GRP_US;
        float hv4[4];
        #pragma unroll
        for (int i = 0; i < 4; ++i) {              // ring publish first
          float v = ftanh(pa[i] + pb[i]);
          hv4[i] = v;
          __hip_atomic_store(wdst + poff + (quad*4 + i)*32, f2bf(v),
                             __ATOMIC_RELAXED, __HIP_MEMORY_SCOPE_AGENT);
        }
        asm volatile("s_waitcnt vmcnt(0)" ::: "memory");
        __builtin_amdgcn_sched_barrier(0);
        __hip_atomic_store(myep1, t + 1, __ATOMIC_RELAXED, __HIP_MEMORY_SCOPE_AGENT);
        #pragma unroll
        for (int i = 0; i < 4; ++i)                // dout after the epoch
          dout[((size_t)(b0 + quad*4 + i) * T + t) * H + ccol] = hv4[i];
      }
    }
    // one barrier per round; drain LDS writes only (never vmcnt)
    asm volatile("s_waitcnt lgkmcnt(0)\n\ts_barrier" ::: "memory");
    __builtin_amdgcn_sched_barrier(0);
  }
}

#define SMEM_BYTES  ((16384 + 16384) * 2)   // 64KB (rnn)
#define SMEM_GEMM   131072                  // 128KB (gemm)

extern "C" void kernel_launch(void* const* d_in, const int* in_sizes, int n_in,
                              void* d_out, int out_size, void* d_ws, size_t ws_size,
                              hipStream_t stream) {
  const float* x    = (const float*)d_in[0];
  const float* Wih0 = (const float*)d_in[1];
  const float* Whh0 = (const float*)d_in[2];
  const float* Wih1 = (const float*)d_in[3];
  const float* Whh1 = (const float*)d_in[4];
  float* out = (float*)d_out;

  char* ws = (char*)d_ws;
  unsigned short* xwb = (unsigned short*)ws;                           // 32MB
  unsigned short* wp0 = (unsigned short*)(ws + (size_t)32*1024*1024);          // 512KB
  unsigned short* wp1 = (unsigned short*)(ws + (size_t)32*1024*1024 + 512*1024);
  unsigned short* wp2 = (unsigned short*)(ws + (size_t)32*1024*1024 + 1024*1024);
  unsigned short* wpx = (unsigned short*)(ws + (size_t)32*1024*1024 + 1536*1024); // 256KB
  unsigned short* ring0 = (unsigned short*)(ws + (size_t)32*1024*1024 + 1792*1024);
  unsigned short* ring1 = ring0 + RING_US;
  int* flags = (int*)(ring1 + RING_US);

  hipMemsetAsync(flags, 0, NGR * 64 * sizeof(int), stream);
  hipFuncSetAttribute((const void*)rnn_fused,
                      hipFuncAttributeMaxDynamicSharedMemorySize, SMEM_BYTES);
  hipFuncSetAttribute((const void*)gemm_mfma,
                      hipFuncAttributeMaxDynamicSharedMemorySize, SMEM_GEMM);

  pack_w<<<128, 256, 0, stream>>>(Whh0, wp0);
  pack_w<<<128, 256, 0, stream>>>(Wih1, wp1);
  pack_w<<<128, 256, 0, stream>>>(Whh1, wp2);
  pack_wx<<<64, 256, 0, stream>>>(Wih0, wpx);

  dim3 gg(M/64, H/256);
  gemm_mfma<<<gg, 256, SMEM_GEMM, stream>>>(x, wpx, xwb);

  rnn_fused<<<NGR * 16, 256, SMEM_BYTES, stream>>>(
      xwb, wp0, wp1, wp2, ring0, ring1, out, flags);
}

// Round 11
// 1217.167 us; speedup vs baseline: 5.0952x; 4.0123x over previous
//
#include <hip/hip_runtime.h>
#include <math.h>

#define B   64
#define T   512
#define I0  256
#define H   512
#define M   (B*T)

#define NGR 4        // batch groups (16 batches each -> MFMA M=16)
#define BGR 16
#define NCH 16       // col chunks
#define CCH 32       // cols per chunk = 2 MFMA tiles
#define HS_STRIDE 520  // staged-h row stride in ushorts

#define RSLOTS 8                       // ring depth (power of 2)
#define RING_US ((size_t)RSLOTS * B * H)   // ushorts per ring = 512KB

typedef __attribute__((ext_vector_type(8))) short short8;
typedef __attribute__((ext_vector_type(4))) float floatx4;

static __device__ __forceinline__ unsigned short f2bf(float f) {
  unsigned u = __float_as_uint(f);
  u += 0x7fff + ((u >> 16) & 1);          // RNE
  return (unsigned short)(u >> 16);
}
static __device__ __forceinline__ float bf2f(unsigned short u) {
  return __uint_as_float((unsigned)u << 16);
}
// fast tanh: 1 - 2/(e^{2x}+1). |err| ~1e-6, saturates correctly, no NaN.
static __device__ __forceinline__ float ftanh(float x) {
  float e = __expf(2.0f * x);
  return 1.0f - 2.0f * __builtin_amdgcn_rcpf(e + 1.0f);
}

// ---------------------------------------------------------------------------
// Pack [H,H] fp32 weight into bf16 B-fragment lane order.
// dst layout [tile=32][kt=16][lane=64][8 us]
// ---------------------------------------------------------------------------
__global__ __launch_bounds__(256)
void pack_w(const float* __restrict__ W, unsigned short* __restrict__ dst) {
  int idx = blockIdx.x * 256 + threadIdx.x;   // over 16*2*16*64 = 32768
  int l = idx & 63, i = (idx >> 6) & 15, tau = (idx >> 10) & 1, c = idx >> 11;
  int col = c * CCH + tau * 16 + (l & 15);
  int k0  = i * 32 + (l >> 4) * 8;
  const float* src = &W[col * H + k0];
  unsigned v[4];
  #pragma unroll
  for (int j = 0; j < 4; ++j) {
    unsigned lo = f2bf(src[2*j]);
    unsigned hi = f2bf(src[2*j + 1]);
    v[j] = lo | (hi << 16);
  }
  *(uint4*)&dst[(size_t)idx * 8] = make_uint4(v[0], v[1], v[2], v[3]);
}

// ---------------------------------------------------------------------------
// Pack Wih0 [H][I0] fp32 -> bf16 B-frags: [tile=32][kt=8][lane=64][8 us]
// ---------------------------------------------------------------------------
__global__ __launch_bounds__(256)
void pack_wx(const float* __restrict__ W, unsigned short* __restrict__ dst) {
  int idx = blockIdx.x * 256 + threadIdx.x;   // over 32*8*64 = 16384
  int l = idx & 63, kt = (idx >> 6) & 7, t = idx >> 9;
  int col = t * 16 + (l & 15);
  int k0  = kt * 32 + (l >> 4) * 8;
  const float* src = &W[col * I0 + k0];
  unsigned v[4];
  #pragma unroll
  for (int j = 0; j < 4; ++j) {
    unsigned lo = f2bf(src[2*j]);
    unsigned hi = f2bf(src[2*j + 1]);
    v[j] = lo | (hi << 16);
  }
  *(uint4*)&dst[(size_t)idx * 8] = make_uint4(v[0], v[1], v[2], v[3]);
}

// ---------------------------------------------------------------------------
// MFMA input-projection GEMM: xwb[M][H] = bf16( x[M][I0] @ Wih0^T ).
// Split-A (x = hi + lo bf16) keeps accuracy at the fp32-GEMM level.
// Proven correct in rounds 8/10 (absmax unchanged).
// ---------------------------------------------------------------------------
__global__ __launch_bounds__(256)
void gemm_mfma(const float* __restrict__ x, const unsigned short* __restrict__ wpx,
               unsigned short* __restrict__ xwb) {
  extern __shared__ unsigned short wl[];   // [16 tiles][8 kt][64][8] = 128KB
  const int tid = threadIdx.x, wv = tid >> 6, lane = tid & 63;
  const int mrow = lane & 15, quad = lane >> 4;
  const int m0 = blockIdx.x * 64 + wv * 16;
  const int n0 = blockIdx.y * 256;
  {
    const uint4* s = (const uint4*)(wpx + (size_t)(n0 / 16) * 4096);
    uint4* d = (uint4*)wl;
    for (int i = tid; i < 8192; i += 256) d[i] = s[i];
  }
  short8 ah[8], al[8];
  const float* xr = x + (size_t)(m0 + mrow) * I0;
  #pragma unroll
  for (int kt = 0; kt < 8; ++kt) {
    float4 u = *(const float4*)&xr[kt * 32 + quad * 8];
    float4 v = *(const float4*)&xr[kt * 32 + quad * 8 + 4];
    float f[8] = {u.x,u.y,u.z,u.w,v.x,v.y,v.z,v.w};
    union { unsigned w[4]; short8 s; } hi, lo;
    #pragma unroll
    for (int j = 0; j < 4; ++j) {
      unsigned short h0 = f2bf(f[2*j]),   l0 = f2bf(f[2*j]   - bf2f(h0));
      unsigned short h1 = f2bf(f[2*j+1]), l1 = f2bf(f[2*j+1] - bf2f(h1));
      hi.w[j] = (unsigned)h0 | ((unsigned)h1 << 16);
      lo.w[j] = (unsigned)l0 | ((unsigned)l1 << 16);
    }
    ah[kt] = hi.s; al[kt] = lo.s;
  }
  __syncthreads();
  for (int ct = 0; ct < 16; ++ct) {
    floatx4 acc = {0.f,0.f,0.f,0.f};
    #pragma unroll
    for (int kt = 0; kt < 8; ++kt) {
      short8 b = *(const short8*)(wl + ((size_t)(ct * 8 + kt) * 64 + lane) * 8);
      acc = __builtin_amdgcn_mfma_f32_16x16x32_bf16(al[kt], b, acc, 0, 0, 0);
      acc = __builtin_amdgcn_mfma_f32_16x16x32_bf16(ah[kt], b, acc, 0, 0, 0);
    }
    #pragma unroll
    for (int i = 0; i < 4; ++i)
      xwb[(size_t)(m0 + quad*4 + i) * H + n0 + ct*16 + mrow] = f2bf(acc[i]);
  }
}

// ---------------------------------------------------------------------------
// Fused 2-layer pipelined persistent recurrence — ROUND-1's 1171us kernel,
// VERBATIM, except: (a) xw input is bf16, (b) tanhf -> ftanh. The protocol
// (cooperative sentinel data-poll over both rings -> LDS stage -> lgkm
// barrier -> MFMA -> fire-and-forget publish + re-arm -> raw barrier) is
// the measured local optimum across 10 protocol variants (2.29us/step).
// ---------------------------------------------------------------------------
__global__ __launch_bounds__(256)
void rnn_fused(const unsigned short* __restrict__ xwb,  // [B][T][H] bf16
               const unsigned short* __restrict__ wp0,  // Whh0 packed
               const unsigned short* __restrict__ wp1,  // Wih1 packed
               const unsigned short* __restrict__ wp2,  // Whh1 packed
               unsigned short* __restrict__ ring0,      // [8][B][H] bf16
               unsigned short* __restrict__ ring1,      // [8][B][H] bf16
               float* __restrict__ dout)                // [B][T][H]
{
  extern __shared__ unsigned short smem[];
  unsigned short* Ws0 = smem;             // [2][16][64][8] = 16384 us
  unsigned short* Wi1 = Ws0 + 16384;
  unsigned short* Ws1 = Wi1 + 16384;
  unsigned short* hs0 = Ws1 + 16384;      // [16][HS_STRIDE]
  unsigned short* hs1 = hs0 + 8320;

  const int tid   = threadIdx.x;
  const int g     = blockIdx.x & 3;
  const int chunk = blockIdx.x >> 2;
  const int c0    = chunk * CCH;
  const int b0    = g * BGR;
  const int wv    = tid >> 6;
  const int lane  = tid & 63;
  const int mrow  = lane & 15;
  const int quad  = lane >> 4;

  // stage packed weight slices
  {
    const uint4* s0 = (const uint4*)(wp0 + (size_t)chunk * 16384);
    const uint4* s1 = (const uint4*)(wp1 + (size_t)chunk * 16384);
    const uint4* s2 = (const uint4*)(wp2 + (size_t)chunk * 16384);
    uint4* d0 = (uint4*)Ws0; uint4* d1 = (uint4*)Wi1; uint4* d2 = (uint4*)Ws1;
    for (int i = tid; i < 2048; i += 256) { d0[i] = s0[i]; d1[i] = s1[i]; d2[i] = s2[i]; }
  }
  // zero hs1 (read by layer-2 MFMA at r==1 before first staging)
  for (int i = tid; i < 2080; i += 256) ((unsigned long long*)hs1)[i] = 0ULL;
  __syncthreads();

  long cnt = 0;   // kernel-wide poll budget (watchdog; bails instead of hang)

  for (int r = 0; r <= T; ++r) {
    // ---- xw prefetch: independent of the recurrence, overlap with poll
    unsigned short xus[4];
    if (wv < 2 && r < T) {
      const int ccol = c0 + wv * 16 + mrow;
      #pragma unroll
      for (int i = 0; i < 4; ++i)
        xus[i] = xwb[((size_t)(b0 + quad * 4 + i) * T + r) * H + ccol];
    }

    // ---- poll the ring DATA until sentinel-free; winning loads ARE the data
    unsigned long long v0[8], v1[8];
    if (r >= 1) {
      const unsigned long long* s0 =
          (const unsigned long long*)(ring0 + (size_t)((r - 1) & (RSLOTS - 1)) * (B * H))
          + b0 * 128;
      const unsigned long long* s1 =
          (const unsigned long long*)(ring1 + (size_t)((r - 2) & (RSLOTS - 1)) * (B * H))
          + b0 * 128;
      const bool need1 = (r >= 2);
      for (;;) {
        #pragma unroll
        for (int j = 0; j < 8; ++j)
          v0[j] = __hip_atomic_load(s0 + j * 256 + tid,
                                    __ATOMIC_RELAXED, __HIP_MEMORY_SCOPE_AGENT);
        if (need1) {
          #pragma unroll
          for (int j = 0; j < 8; ++j)
            v1[j] = __hip_atomic_load(s1 + j * 256 + tid,
                                      __ATOMIC_RELAXED, __HIP_MEMORY_SCOPE_AGENT);
        }
        unsigned long long bad = 0;
        #pragma unroll
        for (int j = 0; j < 8; ++j) {   // any halfword == 0xFFFF ?
          unsigned long long w = ~v0[j];
          bad |= (w - 0x0001000100010001ULL) & ~w & 0x8000800080008000ULL;
        }
        if (need1) {
          #pragma unroll
          for (int j = 0; j < 8; ++j) {
            unsigned long long w = ~v1[j];
            bad |= (w - 0x0001000100010001ULL) & ~w & 0x8000800080008000ULL;
          }
        }
        if (bad == 0 || ++cnt > 2000000L) break;
      }
      // ---- stage to LDS from the poll registers
      #pragma unroll
      for (int j = 0; j < 8; ++j) {
        int ii = j * 256 + tid, row = ii >> 7, c8 = ii & 127;
        *(unsigned long long*)&hs0[row * HS_STRIDE + c8 * 4] = v0[j];
      }
      if (need1) {
        #pragma unroll
        for (int j = 0; j < 8; ++j) {
          int ii = j * 256 + tid, row = ii >> 7, c8 = ii & 127;
          *(unsigned long long*)&hs1[row * HS_STRIDE + c8 * 4] = v1[j];
        }
      }
    }
    // staging visible to all waves; NO vmcnt drain (fire-and-forget stores)
    asm volatile("s_waitcnt lgkmcnt(0)\n\ts_barrier" ::: "memory");
    __builtin_amdgcn_sched_barrier(0);

    // ---- compute ----
    if (wv < 2) {                       // layer 1, tile wv
      if (r < T) {
        floatx4 acc = {0.f, 0.f, 0.f, 0.f};
        if (r >= 1) {
          const unsigned short* wb = Ws0 + wv * 8192;
          const unsigned short* ha = hs0 + mrow * HS_STRIDE + quad * 8;
          #pragma unroll
          for (int i = 0; i < 16; ++i) {
            short8 a = *(const short8*)(ha + i * 32);
            short8 b = *(const short8*)(wb + (i * 64 + lane) * 8);
            acc = __builtin_amdgcn_mfma_f32_16x16x32_bf16(a, b, acc, 0, 0, 0);
          }
        }
        const int ccol = c0 + wv * 16 + mrow;
        unsigned short* rdst = ring0 + (size_t)(r & (RSLOTS - 1)) * (B * H);
        unsigned short* rrst = ring0 + (size_t)((r + 4) & (RSLOTS - 1)) * (B * H);
        #pragma unroll
        for (int i = 0; i < 4; ++i) {
          int b = b0 + quad * 4 + i;
          float h = ftanh(acc[i] + bf2f(xus[i]));
          __hip_atomic_store(rdst + (size_t)b * H + ccol, f2bf(h),
                             __ATOMIC_RELAXED, __HIP_MEMORY_SCOPE_AGENT);
        }
        // reset own addresses 4 rounds ahead (same-thread same-addr ordered)
        #pragma unroll
        for (int i = 0; i < 4; ++i) {
          int b = b0 + quad * 4 + i;
          __hip_atomic_store(rrst + (size_t)b * H + ccol, (unsigned short)0xFFFFu,
                             __ATOMIC_RELAXED, __HIP_MEMORY_SCOPE_AGENT);
        }
      }
    } else {                            // layer 2, tile wv-2, step t2 = r-1
      if (r >= 1) {
        floatx4 acc = {0.f, 0.f, 0.f, 0.f};
        const int tt = wv - 2;
        const unsigned short* wi  = Wi1 + tt * 8192;
        const unsigned short* wh  = Ws1 + tt * 8192;
        const unsigned short* ha0 = hs0 + mrow * HS_STRIDE + quad * 8;
        const unsigned short* ha1 = hs1 + mrow * HS_STRIDE + quad * 8;
        #pragma unroll
        for (int i = 0; i < 16; ++i) {
          short8 a = *(const short8*)(ha0 + i * 32);
          short8 b = *(const short8*)(wi + (i * 64 + lane) * 8);
          acc = __builtin_amdgcn_mfma_f32_16x16x32_bf16(a, b, acc, 0, 0, 0);
        }
        #pragma unroll
        for (int i = 0; i < 16; ++i) {
          short8 a = *(const short8*)(ha1 + i * 32);
          short8 b = *(const short8*)(wh + (i * 64 + lane) * 8);
          acc = __builtin_amdgcn_mfma_f32_16x16x32_bf16(a, b, acc, 0, 0, 0);
        }
        const int ccol = c0 + tt * 16 + mrow;
        const int t2 = r - 1;
        unsigned short* rdst = ring1 + (size_t)(t2 & (RSLOTS - 1)) * (B * H);
        unsigned short* rrst = ring1 + (size_t)((t2 + 4) & (RSLOTS - 1)) * (B * H);
        float hv[4];
        #pragma unroll
        for (int i = 0; i < 4; ++i) {   // ring store first: consumer latency
          int b = b0 + quad * 4 + i;
          float h = ftanh(acc[i]);
          hv[i] = h;
          __hip_atomic_store(rdst + (size_t)b * H + ccol, f2bf(h),
                             __ATOMIC_RELAXED, __HIP_MEMORY_SCOPE_AGENT);
        }
        #pragma unroll
        for (int i = 0; i < 4; ++i) {
          int b = b0 + quad * 4 + i;
          dout[((size_t)b * T + t2) * H + ccol] = hv[i];
          __hip_atomic_store(rrst + (size_t)b * H + ccol, (unsigned short)0xFFFFu,
                             __ATOMIC_RELAXED, __HIP_MEMORY_SCOPE_AGENT);
        }
      }
    }
    // protect hs0/hs1 for next round's staging; ds_reads already consumed
    // by MFMA data-deps, so no waitcnt needed here.
    asm volatile("s_barrier" ::: "memory");
  }
}

#define SMEM_BYTES ((3 * 16384 + 2 * 8320) * 2)   // 131584
#define SMEM_GEMM  131072                          // 128KB

extern "C" void kernel_launch(void* const* d_in, const int* in_sizes, int n_in,
                              void* d_out, int out_size, void* d_ws, size_t ws_size,
                              hipStream_t stream) {
  const float* x    = (const float*)d_in[0];
  const float* Wih0 = (const float*)d_in[1];
  const float* Whh0 = (const float*)d_in[2];
  const float* Wih1 = (const float*)d_in[3];
  const float* Whh1 = (const float*)d_in[4];
  float* out = (float*)d_out;

  char* ws = (char*)d_ws;
  unsigned short* xwb = (unsigned short*)ws;                                    // 32MB
  unsigned short* wp0 = (unsigned short*)(ws + (size_t)32*1024*1024);           // 512KB
  unsigned short* wp1 = (unsigned short*)(ws + (size_t)32*1024*1024 + 512*1024);
  unsigned short* wp2 = (unsigned short*)(ws + (size_t)32*1024*1024 + 1024*1024);
  unsigned short* wpx = (unsigned short*)(ws + (size_t)32*1024*1024 + 1536*1024); // 256KB
  unsigned short* ring0 = (unsigned short*)(ws + (size_t)32*1024*1024 + 1792*1024);
  unsigned short* ring1 = ring0 + RING_US;

  // sentinel-fill both rings (0xFFFF bf16 = -NaN; tanh never produces it)
  hipMemsetAsync(ring0, 0xFF, 2 * RING_US * sizeof(unsigned short), stream);
  hipFuncSetAttribute((const void*)rnn_fused,
                      hipFuncAttributeMaxDynamicSharedMemorySize, SMEM_BYTES);
  hipFuncSetAttribute((const void*)gemm_mfma,
                      hipFuncAttributeMaxDynamicSharedMemorySize, SMEM_GEMM);

  pack_w<<<128, 256, 0, stream>>>(Whh0, wp0);
  pack_w<<<128, 256, 0, stream>>>(Wih1, wp1);
  pack_w<<<128, 256, 0, stream>>>(Whh1, wp2);
  pack_wx<<<64, 256, 0, stream>>>(Wih0, wpx);

  dim3 gg(M/64, H/256);
  gemm_mfma<<<gg, 256, SMEM_GEMM, stream>>>(x, wpx, xwb);

  rnn_fused<<<NGR * NCH, 256, SMEM_BYTES, stream>>>(
      xwb, wp0, wp1, wp2, ring0, ring1, out);
}

// Round 12
// 1199.516 us; speedup vs baseline: 5.1701x; 1.0147x over previous
//
#include <hip/hip_runtime.h>
#include <math.h>

#define B   64
#define T   512
#define I0  256
#define H   512
#define M   (B*T)

#define NGR 4        // batch groups (16 batches each -> MFMA M=16)
#define BGR 16
#define NCH 16       // col chunks
#define CCH 32       // cols per chunk = 2 MFMA tiles

#define RSLOTS 8                       // ring depth (power of 2)
#define RING_US ((size_t)RSLOTS * B * H)   // ushorts per ring = 512KB

typedef __attribute__((ext_vector_type(8))) short short8;
typedef __attribute__((ext_vector_type(4))) float floatx4;
typedef unsigned long long u64;

static __device__ __forceinline__ unsigned short f2bf(float f) {
  unsigned u = __float_as_uint(f);
  u += 0x7fff + ((u >> 16) & 1);          // RNE
  return (unsigned short)(u >> 16);
}
static __device__ __forceinline__ float bf2f(unsigned short u) {
  return __uint_as_float((unsigned)u << 16);
}
// fast tanh: 1 - 2/(e^{2x}+1). |err| ~1e-6, saturates correctly, no NaN.
static __device__ __forceinline__ float ftanh(float x) {
  float e = __expf(2.0f * x);
  return 1.0f - 2.0f * __builtin_amdgcn_rcpf(e + 1.0f);
}

// ---------------------------------------------------------------------------
// Fused packing: blocks [0,384) pack the three [H][H] weights into bf16
// B-frag order [tile=32][kt=16][lane=64][8us]; blocks [384,448) pack
// Wih0 [H][I0] into [tile=32][kt=8][lane=64][8us]. One launch, not four.
// ---------------------------------------------------------------------------
__global__ __launch_bounds__(256)
void pack_all(const float* __restrict__ Whh0, const float* __restrict__ Wih1,
              const float* __restrict__ Whh1, const float* __restrict__ Wih0,
              unsigned short* __restrict__ wp0, unsigned short* __restrict__ wp1,
              unsigned short* __restrict__ wp2, unsigned short* __restrict__ wpx) {
  const int bk = blockIdx.x, tid = threadIdx.x;
  if (bk < 384) {
    const float* W = (bk < 128) ? Whh0 : (bk < 256) ? Wih1 : Whh1;
    unsigned short* dst = (bk < 128) ? wp0 : (bk < 256) ? wp1 : wp2;
    int idx = (bk & 127) * 256 + tid;       // over 32768
    int l = idx & 63, i = (idx >> 6) & 15, tau = (idx >> 10) & 1, c = idx >> 11;
    int col = c * CCH + tau * 16 + (l & 15);
    int k0  = i * 32 + (l >> 4) * 8;
    const float* src = &W[col * H + k0];
    unsigned v[4];
    #pragma unroll
    for (int j = 0; j < 4; ++j) {
      unsigned lo = f2bf(src[2*j]);
      unsigned hi = f2bf(src[2*j + 1]);
      v[j] = lo | (hi << 16);
    }
    *(uint4*)&dst[(size_t)idx * 8] = make_uint4(v[0], v[1], v[2], v[3]);
  } else {
    int idx = (bk - 384) * 256 + tid;       // over 16384
    int l = idx & 63, kt = (idx >> 6) & 7, t = idx >> 9;
    int col = t * 16 + (l & 15);
    int k0  = kt * 32 + (l >> 4) * 8;
    const float* src = &Wih0[col * I0 + k0];
    unsigned v[4];
    #pragma unroll
    for (int j = 0; j < 4; ++j) {
      unsigned lo = f2bf(src[2*j]);
      unsigned hi = f2bf(src[2*j + 1]);
      v[j] = lo | (hi << 16);
    }
    *(uint4*)&wpx[(size_t)idx * 8] = make_uint4(v[0], v[1], v[2], v[3]);
  }
}

// ---------------------------------------------------------------------------
// MFMA input-projection GEMM: xwb[M][H] = bf16( x[M][I0] @ Wih0^T ).
// Split-A (x = hi + lo bf16) keeps fp32-GEMM-level accuracy (proven R8/R10).
// No LDS: B-frags read coalesced (16B/lane) from the 256KB L2-resident wpx.
// ---------------------------------------------------------------------------
__global__ __launch_bounds__(256)
void gemm_mfma(const float* __restrict__ x, const unsigned short* __restrict__ wpx,
               unsigned short* __restrict__ xwb) {
  const int tid = threadIdx.x, wv = tid >> 6, lane = tid & 63;
  const int mrow = lane & 15, quad = lane >> 4;
  const int m0 = blockIdx.x * 64 + wv * 16;
  const int n0 = blockIdx.y * 256;
  short8 ah[8], al[8];
  const float* xr = x + (size_t)(m0 + mrow) * I0;
  #pragma unroll
  for (int kt = 0; kt < 8; ++kt) {
    float4 u = *(const float4*)&xr[kt * 32 + quad * 8];
    float4 v = *(const float4*)&xr[kt * 32 + quad * 8 + 4];
    float f[8] = {u.x,u.y,u.z,u.w,v.x,v.y,v.z,v.w};
    union { unsigned w[4]; short8 s; } hi, lo;
    #pragma unroll
    for (int j = 0; j < 4; ++j) {
      unsigned short h0 = f2bf(f[2*j]),   l0 = f2bf(f[2*j]   - bf2f(h0));
      unsigned short h1 = f2bf(f[2*j+1]), l1 = f2bf(f[2*j+1] - bf2f(h1));
      hi.w[j] = (unsigned)h0 | ((unsigned)h1 << 16);
      lo.w[j] = (unsigned)l0 | ((unsigned)l1 << 16);
    }
    ah[kt] = hi.s; al[kt] = lo.s;
  }
  for (int ct = 0; ct < 16; ++ct) {
    const unsigned short* wb = wpx + (size_t)(n0 / 16 + ct) * 4096;
    floatx4 acc = {0.f,0.f,0.f,0.f};
    #pragma unroll
    for (int kt = 0; kt < 8; ++kt) {
      short8 b = *(const short8*)(wb + ((size_t)(kt * 64 + lane)) * 8);
      acc = __builtin_amdgcn_mfma_f32_16x16x32_bf16(al[kt], b, acc, 0, 0, 0);
      acc = __builtin_amdgcn_mfma_f32_16x16x32_bf16(ah[kt], b, acc, 0, 0, 0);
    }
    #pragma unroll
    for (int i = 0; i < 4; ++i)
      xwb[(size_t)(m0 + quad*4 + i) * H + n0 + ct*16 + mrow] = f2bf(acc[i]);
  }
}

// ---------------------------------------------------------------------------
// Fused 2-layer pipelined persistent recurrence. PROTOCOL IS R11's,
// byte-identical (cooperative sentinel data-poll over both rings ->
// stage -> lgkm barrier -> MFMA -> fire-and-forget publish + re-arm).
// Changes vs R11 (all off-protocol):
//  1. hs staged in A-FRAGMENT layout [kt=16][lane=64][16B] with per-kt XOR
//     swizzle (slot ^= kt&7): ds_read_b128 becomes lane-contiguous
//     (conflict-free, same pattern as the proven weight reads); the write
//     side lands at the 4-access/bank floor. Kills the 1.26e7 conflicts.
//  2. Whh0/Whh1 in VGPRs (wreg, R6/R10-proven) -> Ws0/Ws1 LDS freed.
//  3. hs double-buffered by round parity (96KB total LDS) -> the trailing
//     s_barrier is removable (stage writes buf p^1, compute reads buf p).
// ---------------------------------------------------------------------------
__global__ __launch_bounds__(256)
void rnn_fused(const unsigned short* __restrict__ xwb,  // [B][T][H] bf16
               const unsigned short* __restrict__ wp0,  // Whh0 packed
               const unsigned short* __restrict__ wp1,  // Wih1 packed
               const unsigned short* __restrict__ wp2,  // Whh1 packed
               unsigned short* __restrict__ ring0,      // [8][B][H] bf16
               unsigned short* __restrict__ ring1,      // [8][B][H] bf16
               float* __restrict__ dout)                // [B][T][H]
{
  extern __shared__ unsigned short smem[];
  unsigned short* Wi1 = smem;             // [2 tiles][16][64][8] = 16384 us
  unsigned short* hs0 = Wi1 + 16384;      // [2][16][64][8] frag dbuf
  unsigned short* hs1 = hs0 + 16384;      // [2][16][64][8] frag dbuf

  const int tid   = threadIdx.x;
  const int g     = blockIdx.x & 3;
  const int chunk = blockIdx.x >> 2;
  const int c0    = chunk * CCH;
  const int b0    = g * BGR;
  const int wv    = tid >> 6;
  const int lane  = tid & 63;
  const int mrow  = lane & 15;
  const int quad  = lane >> 4;

  {   // stage Wih1 tile pair (only LDS-resident weight now)
    const uint4* s1 = (const uint4*)(wp1 + (size_t)chunk * 16384);
    uint4* d1 = (uint4*)Wi1;
    for (int i = tid; i < 2048; i += 256) d1[i] = s1[i];
  }
  // recurrence weights -> registers (L1 waves: Whh0 tile; L2 waves: Whh1)
  short8 wreg[16];
  {
    const unsigned short* wsrc = (wv < 2) ? wp0 : wp2;
    const int tvg = chunk * 2 + (wv & 1);
    #pragma unroll
    for (int kt = 0; kt < 16; ++kt)
      wreg[kt] = *(const short8*)(wsrc + (size_t)((tvg*16 + kt)*64 + lane) * 8);
  }
  // zero hs1 (both parity bufs; read by L2 at r==1 before first staging)
  for (int i = tid; i < 4096; i += 256) ((u64*)hs1)[i] = 0ULL;
  __syncthreads();

  long cnt = 0;   // kernel-wide poll budget (watchdog; bails instead of hang)

  for (int r = 0; r <= T; ++r) {
    // ---- xw prefetch: independent of the recurrence, overlap with poll
    unsigned short xus[4];
    if (wv < 2 && r < T) {
      const int ccol = c0 + wv * 16 + mrow;
      #pragma unroll
      for (int i = 0; i < 4; ++i)
        xus[i] = xwb[((size_t)(b0 + quad * 4 + i) * T + r) * H + ccol];
    }

    // ---- poll the ring DATA until sentinel-free; winning loads ARE the data
    u64 v0[8], v1[8];
    const bool need1 = (r >= 2);
    if (r >= 1) {
      const u64* s0 =
          (const u64*)(ring0 + (size_t)((r - 1) & (RSLOTS - 1)) * (B * H))
          + b0 * 128;
      const u64* s1 =
          (const u64*)(ring1 + (size_t)((r - 2) & (RSLOTS - 1)) * (B * H))
          + b0 * 128;
      for (;;) {
        #pragma unroll
        for (int j = 0; j < 8; ++j)
          v0[j] = __hip_atomic_load(s0 + j * 256 + tid,
                                    __ATOMIC_RELAXED, __HIP_MEMORY_SCOPE_AGENT);
        if (need1) {
          #pragma unroll
          for (int j = 0; j < 8; ++j)
            v1[j] = __hip_atomic_load(s1 + j * 256 + tid,
                                      __ATOMIC_RELAXED, __HIP_MEMORY_SCOPE_AGENT);
        }
        u64 bad = 0;
        #pragma unroll
        for (int j = 0; j < 8; ++j) {   // any halfword == 0xFFFF ?
          u64 w = ~v0[j];
          bad |= (w - 0x0001000100010001ULL) & ~w & 0x8000800080008000ULL;
        }
        if (need1) {
          #pragma unroll
          for (int j = 0; j < 8; ++j) {
            u64 w = ~v1[j];
            bad |= (w - 0x0001000100010001ULL) & ~w & 0x8000800080008000ULL;
          }
        }
        if (bad == 0 || ++cnt > 2000000L) break;
      }
      // ---- stage to A-frag-layout dbuf (XOR-swizzled; see header comment)
      const int p = r & 1;
      u64* H0 = (u64*)hs0 + p * 2048;
      #pragma unroll
      for (int j = 0; j < 8; ++j) {
        int ii = j * 256 + tid, row = ii >> 7, c8 = ii & 127;
        int kt = c8 >> 3, q2 = (c8 & 7) >> 1;
        int slot = kt * 64 + q2 * 16 + row;
        H0[(((slot ^ (kt & 7)) << 1) | (c8 & 1))] = v0[j];
      }
      if (need1) {
        u64* H1 = (u64*)hs1 + p * 2048;
        #pragma unroll
        for (int j = 0; j < 8; ++j) {
          int ii = j * 256 + tid, row = ii >> 7, c8 = ii & 127;
          int kt = c8 >> 3, q2 = (c8 & 7) >> 1;
          int slot = kt * 64 + q2 * 16 + row;
          H1[(((slot ^ (kt & 7)) << 1) | (c8 & 1))] = v1[j];
        }
      }
    }
    // staging visible to all waves; NO vmcnt drain (fire-and-forget stores)
    asm volatile("s_waitcnt lgkmcnt(0)\n\ts_barrier" ::: "memory");
    __builtin_amdgcn_sched_barrier(0);

    // ---- compute ----
    if (wv < 2) {                       // layer 1, tile wv
      if (r < T) {
        floatx4 acc = {0.f, 0.f, 0.f, 0.f};
        if (r >= 1) {
          const unsigned short* hb = hs0 + (r & 1) * 8192;
          #pragma unroll
          for (int kt = 0; kt < 16; ++kt) {
            short8 a = *(const short8*)(hb + ((size_t)((kt*64 + lane) ^ (kt & 7))) * 8);
            acc = __builtin_amdgcn_mfma_f32_16x16x32_bf16(a, wreg[kt], acc, 0, 0, 0);
          }
        }
        const int ccol = c0 + wv * 16 + mrow;
        unsigned short* rdst = ring0 + (size_t)(r & (RSLOTS - 1)) * (B * H);
        unsigned short* rrst = ring0 + (size_t)((r + 4) & (RSLOTS - 1)) * (B * H);
        #pragma unroll
        for (int i = 0; i < 4; ++i) {
          int b = b0 + quad * 4 + i;
          float h = ftanh(acc[i] + bf2f(xus[i]));
          __hip_atomic_store(rdst + (size_t)b * H + ccol, f2bf(h),
                             __ATOMIC_RELAXED, __HIP_MEMORY_SCOPE_AGENT);
        }
        // reset own addresses 4 rounds ahead (same-thread same-addr ordered)
        #pragma unroll
        for (int i = 0; i < 4; ++i) {
          int b = b0 + quad * 4 + i;
          __hip_atomic_store(rrst + (size_t)b * H + ccol, (unsigned short)0xFFFFu,
                             __ATOMIC_RELAXED, __HIP_MEMORY_SCOPE_AGENT);
        }
      }
    } else {                            // layer 2, tile wv-2, step t2 = r-1
      if (r >= 1) {
        floatx4 acc = {0.f, 0.f, 0.f, 0.f};
        const int tt = wv - 2;
        const unsigned short* wi  = Wi1 + tt * 8192;
        const unsigned short* hb0 = hs0 + (r & 1) * 8192;
        const unsigned short* hb1 = hs1 + (r & 1) * 8192;
        #pragma unroll
        for (int kt = 0; kt < 16; ++kt) {
          short8 a = *(const short8*)(hb0 + ((size_t)((kt*64 + lane) ^ (kt & 7))) * 8);
          short8 b = *(const short8*)(wi + ((size_t)(kt * 64 + lane)) * 8);
          acc = __builtin_amdgcn_mfma_f32_16x16x32_bf16(a, b, acc, 0, 0, 0);
        }
        #pragma unroll
        for (int kt = 0; kt < 16; ++kt) {
          short8 a = *(const short8*)(hb1 + ((size_t)((kt*64 + lane) ^ (kt & 7))) * 8);
          acc = __builtin_amdgcn_mfma_f32_16x16x32_bf16(a, wreg[kt], acc, 0, 0, 0);
        }
        const int ccol = c0 + tt * 16 + mrow;
        const int t2 = r - 1;
        unsigned short* rdst = ring1 + (size_t)(t2 & (RSLOTS - 1)) * (B * H);
        unsigned short* rrst = ring1 + (size_t)((t2 + 4) & (RSLOTS - 1)) * (B * H);
        float hv[4];
        #pragma unroll
        for (int i = 0; i < 4; ++i) {   // ring store first: consumer latency
          int b = b0 + quad * 4 + i;
          float h = ftanh(acc[i]);
          hv[i] = h;
          __hip_atomic_store(rdst + (size_t)b * H + ccol, f2bf(h),
                             __ATOMIC_RELAXED, __HIP_MEMORY_SCOPE_AGENT);
        }
        #pragma unroll
        for (int i = 0; i < 4; ++i) {
          int b = b0 + quad * 4 + i;
          dout[((size_t)b * T + t2) * H + ccol] = hv[i];
          __hip_atomic_store(rrst + (size_t)b * H + ccol, (unsigned short)0xFFFFu,
                             __ATOMIC_RELAXED, __HIP_MEMORY_SCOPE_AGENT);
        }
      }
    }
    // no trailing barrier: next round stages into buf p^1 (disjoint from the
    // buf p this round's compute reads); barrier1 orders stage vs compute.
  }
}

#define SMEM_BYTES ((16384 + 16384 + 16384) * 2)   // 98304

extern "C" void kernel_launch(void* const* d_in, const int* in_sizes, int n_in,
                              void* d_out, int out_size, void* d_ws, size_t ws_size,
                              hipStream_t stream) {
  const float* x    = (const float*)d_in[0];
  const float* Wih0 = (const float*)d_in[1];
  const float* Whh0 = (const float*)d_in[2];
  const float* Wih1 = (const float*)d_in[3];
  const float* Whh1 = (const float*)d_in[4];
  float* out = (float*)d_out;

  char* ws = (char*)d_ws;
  unsigned short* xwb = (unsigned short*)ws;                                    // 32MB
  unsigned short* wp0 = (unsigned short*)(ws + (size_t)32*1024*1024);           // 512KB
  unsigned short* wp1 = (unsigned short*)(ws + (size_t)32*1024*1024 + 512*1024);
  unsigned short* wp2 = (unsigned short*)(ws + (size_t)32*1024*1024 + 1024*1024);
  unsigned short* wpx = (unsigned short*)(ws + (size_t)32*1024*1024 + 1536*1024); // 256KB
  unsigned short* ring0 = (unsigned short*)(ws + (size_t)32*1024*1024 + 1792*1024);
  unsigned short* ring1 = ring0 + RING_US;

  // sentinel-fill both rings (0xFFFF bf16 = -NaN; tanh never produces it)
  hipMemsetAsync(ring0, 0xFF, 2 * RING_US * sizeof(unsigned short), stream);
  hipFuncSetAttribute((const void*)rnn_fused,
                      hipFuncAttributeMaxDynamicSharedMemorySize, SMEM_BYTES);

  pack_all<<<448, 256, 0, stream>>>(Whh0, Wih1, Whh1, Wih0, wp0, wp1, wp2, wpx);

  dim3 gg(M/64, H/256);
  gemm_mfma<<<gg, 256, 0, stream>>>(x, wpx, xwb);

  rnn_fused<<<NGR * NCH, 256, SMEM_BYTES, stream>>>(
      xwb, wp0, wp1, wp2, ring0, ring1, out);
}